// Round 2
// baseline (285.208 us; speedup 1.0000x reference)
//
#include <hip/hip_runtime.h>
#include <hip/hip_bf16.h>

#define NN 256          // Preisach mesh size (n x n thresholds)
#define MAXM 4000       // time steps (M); hs/dir arrays have M+1 entries

__device__ __forceinline__ float softplus_f(float x) {
    // matches np/jax stable softplus well within 2% tolerance
    if (x > 20.0f) return x;
    return log1pf(expf(x));
}

// Build hs[0..M] = [1.0, (h+1)/2 ...] and dir[tau] = sign(hs[tau]-hs[tau-1]) (tau=0 wraps to hs[M]).
__global__ void k_build(const float* __restrict__ h, int M,
                        float* __restrict__ hs, signed char* __restrict__ dir) {
    int idx = blockIdx.x * blockDim.x + threadIdx.x;
    if (idx > M) return;
    float cur  = (idx == 0) ? 1.0f : (h[idx - 1] + 1.0f) * 0.5f;
    float prev;
    if (idx == 0)      prev = (h[M - 1] + 1.0f) * 0.5f; // hs[M]
    else if (idx == 1) prev = 1.0f;                     // hs[0]
    else               prev = (h[idx - 2] + 1.0f) * 0.5f;
    hs[idx]  = cur;
    dir[idx] = (cur > prev) ? (signed char)1 : ((cur < prev) ? (signed char)-1 : (signed char)0);
}

// Per-row prefix sums of dens = softplus(raw) scattered into the lower triangle.
// Pref[i*257 + k] = sum_{j<k} dens[i][j], k in [0, 256]; RowTot[i] = row sum.
__global__ void k_pref(const float* __restrict__ raw,
                       float* __restrict__ Pref, float* __restrict__ RowTot) {
    int i = blockIdx.x;
    int j = threadIdx.x;
    __shared__ float s[NN];
    float v = 0.0f;
    if (j <= i) {
        int base = i * (i + 1) / 2;
        v = softplus_f(raw[base + j]);
    }
    s[j] = v;
    __syncthreads();
    // Hillis-Steele inclusive scan over 256 lanes
    for (int off = 1; off < NN; off <<= 1) {
        float add = (j >= off) ? s[j - off] : 0.0f;
        __syncthreads();
        s[j] += add;
        __syncthreads();
    }
    Pref[i * 257 + j + 1] = s[j];
    if (j == 0)      Pref[i * 257] = 0.0f;
    if (j == NN - 1) RowTot[i] = s[j];
}

__global__ void k_tot(const float* __restrict__ RowTot, float* __restrict__ invTot) {
    __shared__ float s[NN];
    int j = threadIdx.x;
    s[j] = RowTot[j];
    __syncthreads();
    for (int off = NN / 2; off > 0; off >>= 1) {
        if (j < off) s[j] += s[j + off];
        __syncthreads();
    }
    if (j == 0) invTot[0] = 1.0f / s[0];
}

// One block per output index t. Thread tid owns threshold x[tid].
// Backward scan over steps tau = t+1 .. 0 finds U (last up-flip of row tid)
// and D (last down-flip of col tid). State(+1) iff U > D. D is non-decreasing
// in j, so per-row +1 region is a prefix: count via binary search, weight via Pref.
__global__ void __launch_bounds__(256)
k_main(const float* __restrict__ hs_g, const signed char* __restrict__ dir_g,
       const float* __restrict__ Pref, const float* __restrict__ RowTot,
       const float* __restrict__ invTot, float* __restrict__ out, int M) {
    __shared__ float       hs_s[MAXM + 1];
    __shared__ signed char dir_s[MAXM + 4];
    __shared__ int         Dv[NN];
    __shared__ float       red[4];

    int t   = blockIdx.x;   // output index 0..M-1
    int te  = t + 1;        // last step index contributing to states[t+1]
    int tid = threadIdx.x;

    for (int k = tid; k <= te; k += 256) {
        hs_s[k]  = hs_g[k];
        dir_s[k] = dir_g[k];
    }
    __syncthreads();

    float xi = (float)((double)tid / 255.0);  // matches np.linspace(0,1,256) (f64 -> f32)
    int  U = -1, D = -1;
    bool doneU = (tid == NN - 1);  // x=1.0: h > 1.0 impossible
    bool doneD = (tid == 0);       // x=0.0: h < 0.0 impossible

    int tau = te;
    while (true) {
        int stop = tau - 32;
        if (stop < -1) stop = -1;
        for (; tau > stop; --tau) {
            float h = hs_s[tau];
            int   d = dir_s[tau];
            if (!doneU && d > 0 && h > xi) { U = tau; doneU = true; }
            if (!doneD && d < 0 && h < xi) { D = tau; doneD = true; }
        }
        if (tau < 0) break;
        if (__syncthreads_and(doneU && doneD)) break;
    }

    Dv[tid] = D;
    __syncthreads();

    // count of j with D[j] < U  (D sorted non-decreasing; sentinel -1 prefix)
    int lo = 0, hi = NN;
    while (lo < hi) {
        int mid = (lo + hi) >> 1;
        if (Dv[mid] < U) lo = mid + 1; else hi = mid;
    }
    int c = lo;
    if (c > tid + 1) c = tid + 1;  // triangle: only j <= i exists

    float val = 2.0f * Pref[tid * 257 + c] - RowTot[tid];

    // block reduction: wave shuffle then cross-wave via LDS
    for (int off = 32; off > 0; off >>= 1) val += __shfl_down(val, off, 64);
    int wave = tid >> 6;
    if ((tid & 63) == 0) red[wave] = val;
    __syncthreads();
    if (tid == 0) {
        float s = red[0] + red[1] + red[2] + red[3];
        out[t] = s * invTot[0];
    }
}

extern "C" void kernel_launch(void* const* d_in, const int* in_sizes, int n_in,
                              void* d_out, int out_size, void* d_ws, size_t ws_size,
                              hipStream_t stream) {
    const float* h   = (const float*)d_in[0];
    const float* raw = (const float*)d_in[1];
    float* out = (float*)d_out;
    int M = in_sizes[0];  // 4000

    char* ws = (char*)d_ws;
    size_t off = 0;
    auto take = [&](size_t bytes) { size_t cur = off; off = (off + bytes + 255) & ~(size_t)255; return cur; };
    float*       hs     = (float*)(ws + take((size_t)(M + 1) * 4));
    signed char* dir    = (signed char*)(ws + take((size_t)(M + 1)));
    float*       Pref   = (float*)(ws + take((size_t)NN * 257 * 4));
    float*       RowTot = (float*)(ws + take((size_t)NN * 4));
    float*       invTot = (float*)(ws + take(4));

    k_build<<<(M + 1 + 255) / 256, 256, 0, stream>>>(h, M, hs, dir);
    k_pref<<<NN, 256, 0, stream>>>(raw, Pref, RowTot);
    k_tot<<<1, 256, 0, stream>>>(RowTot, invTot);
    k_main<<<M, 256, 0, stream>>>(hs, dir, Pref, RowTot, invTot, out, M);
}

// Round 3
// 102.533 us; speedup vs baseline: 2.7816x; 2.7816x over previous
//
#include <hip/hip_runtime.h>

#define NN 256     // Preisach mesh size
#define TT 16      // outputs (and steps) per chunk

__device__ __forceinline__ float softplus_f(float x) {
    if (x > 20.0f) return x;
    return log1pf(expf(x));
}

// ---- Per-row prefix sums of dens = softplus(raw), stored TRANSPOSED ----
// PrefT[k*NN + i] = sum_{j<k} dens[i][j], k in [0,256]; RowTot[i] = row sum.
__global__ void k_pref(const float* __restrict__ raw,
                       float* __restrict__ PrefT, float* __restrict__ RowTot) {
    int i = blockIdx.x, j = threadIdx.x;
    __shared__ float s[NN];
    float v = 0.0f;
    if (j <= i) v = softplus_f(raw[i * (i + 1) / 2 + j]);
    s[j] = v;
    __syncthreads();
    for (int off = 1; off < NN; off <<= 1) {      // Hillis-Steele inclusive scan
        float add = (j >= off) ? s[j - off] : 0.0f;
        __syncthreads();
        s[j] += add;
        __syncthreads();
    }
    PrefT[(j + 1) * NN + i] = s[j];
    if (j == 0)      PrefT[i] = 0.0f;
    if (j == NN - 1) RowTot[i] = s[j];
}

// ---- Per-chunk: build packed step records + last-flip tables ----
// steps_g[tau] = dir(2b: d+1) | ih<<2 | jh<<11   (ih=#{x<h}, jh=#{x<=h})
// UD_g[b*NN+i] = Ue | De<<16, Ue/De = (last flip tau in chunk)+1, 0 = none.
__global__ void __launch_bounds__(256)
k_chunk(const float* __restrict__ h_g, int M,
        int* __restrict__ steps_g, unsigned int* __restrict__ UD_g) {
    __shared__ float xs[NN];
    __shared__ float hh[TT + 1];
    __shared__ int   dd[TT + 1];
    int b = blockIdx.x, tid = threadIdx.x;
    int t0 = b * TT;
    int Tb = min(TT, M - t0);

    xs[tid] = (float)((double)tid / 255.0);   // matches np.linspace(0,1,256)
    __syncthreads();

    if (tid < Tb) {
        int tau = t0 + 1 + tid;
        float cur  = (h_g[tau - 1] + 1.0f) * 0.5f;
        float prev = (tau == 1) ? 1.0f : (h_g[tau - 2] + 1.0f) * 0.5f;
        int d = (cur > prev) ? 2 : ((cur < prev) ? 0 : 1);
        int lo = 0, hi = NN;                      // ih = count x_i < cur
        while (lo < hi) { int m = (lo + hi) >> 1; if (xs[m] < cur) lo = m + 1; else hi = m; }
        int ih = lo;
        lo = 0; hi = NN;                          // jh = count x_j <= cur
        while (lo < hi) { int m = (lo + hi) >> 1; if (xs[m] <= cur) lo = m + 1; else hi = m; }
        int jh = lo;
        hh[1 + tid] = cur;
        dd[1 + tid] = d - 1;
        steps_g[tau] = d | (ih << 2) | (jh << 11);
    }
    __syncthreads();

    float xi = xs[tid];
    int Ue = 0, De = 0;
    for (int k = 1; k <= Tb; ++k) {
        float hv = hh[k]; int d = dd[k];
        int tau = t0 + k;
        if (d > 0 && hv > xi) Ue = tau + 1;
        if (d < 0 && hv < xi) De = tau + 1;
    }
    UD_g[b * NN + tid] = (unsigned)Ue | ((unsigned)De << 16);
}

// ---- Main: carry-in scan + incremental staircase walk over TT outputs ----
__global__ void __launch_bounds__(256)
k_main(const float* __restrict__ h_g, const int* __restrict__ steps_g,
       const unsigned int* __restrict__ UD_g,
       const float* __restrict__ PrefT, const float* __restrict__ RowTot,
       float* __restrict__ out, int M) {
    __shared__ int   rec_s[TT + 1];
    __shared__ int   Dv[NN];
    __shared__ float red[8];
    int b = blockIdx.x, tid = threadIdx.x;
    int t0 = b * TT;
    int Tb = min(TT, M - t0);

    float hsM = (h_g[M - 1] + 1.0f) * 0.5f;   // hs[M]; dir of step 0 = sign(1 - hsM)
    if (tid < TT) {
        int v = 0;
        if (tid < Tb) v = steps_g[t0 + 1 + tid];
        rec_s[1 + tid] = v;
    }
    float RT = RowTot[tid];
    __syncthreads();

    // prefetch PrefT rows for each step's jh (coalesced, L2-resident)
    float pk[TT + 1];
    #pragma unroll
    for (int k = 1; k <= TT; ++k) {
        int jh = (rec_s[k] >> 11) & 0x1FF;
        pk[k] = PrefT[jh * NN + tid];
    }

    // carry-in: step 0 (h=1.0) then running max over previous chunk tables
    int Ue = 0, De = 0;
    if (hsM < 1.0f && tid < NN - 1) Ue = 1;   // up-step at tau=0 flips rows x_i < 1.0
    const unsigned int* ud = UD_g + tid;
    for (int k = 0; k < b; ++k) {
        unsigned v = ud[k * NN];
        unsigned ue = v & 0xFFFFu, de = v >> 16;
        if (ue > (unsigned)Ue) Ue = (int)ue;
        if (de > (unsigned)De) De = (int)de;
    }
    Dv[tid] = De;
    __syncthreads();

    // c = #{j : De_j < Ue_i} (Dv non-decreasing), clamped to triangle
    int lo = 0, hi = NN;
    while (lo < hi) { int m = (lo + hi) >> 1; if (Dv[m] < Ue) lo = m + 1; else hi = m; }
    int c = min(lo, tid + 1);
    float w = 2.0f * PrefT[c * NN + tid] - RT;   // row i's contribution

    // initial block reduce: S = sum(w), tot = sum(RowTot)
    int wave = tid >> 6;
    float a = w, rb = RT;
    for (int off = 32; off; off >>= 1) {
        a  += __shfl_down(a,  off, 64);
        rb += __shfl_down(rb, off, 64);
    }
    if ((tid & 63) == 0) { red[wave] = a; red[4 + wave] = rb; }
    __syncthreads();
    float S = 0.0f, invTot = 0.0f;
    if (tid == 0) {
        S = red[0] + red[1] + red[2] + red[3];
        invTot = 1.0f / (red[4] + red[5] + red[6] + red[7]);
    }
    __syncthreads();   // red[] reused below

    // forward walk: one output per step
    #pragma unroll
    for (int k = 1; k <= TT; ++k) {
        if (k > Tb) break;           // block-uniform
        int rec = rec_s[k];
        int d = rec & 3;
        float delta = 0.0f;
        if (d == 2) {                               // up-step: rows i < ih -> full +1
            int ih = (rec >> 2) & 0x1FF;
            if (tid < ih) { delta = RT - w; w = RT; c = tid + 1; }
        } else if (d == 0) {                        // down-step: truncate prefix to jh
            int jh = (rec >> 11) & 0x1FF;
            if (c > jh) {
                float wn = 2.0f * pk[k] - RT;
                delta = wn - w; w = wn; c = jh;
            }
        }
        for (int off = 32; off; off >>= 1) delta += __shfl_down(delta, off, 64);
        if ((tid & 63) == 0) red[wave] = delta;
        __syncthreads();
        if (tid == 0) {
            S += red[0] + red[1] + red[2] + red[3];
            out[t0 + k - 1] = S * invTot;
        }
        __syncthreads();
    }
}

extern "C" void kernel_launch(void* const* d_in, const int* in_sizes, int n_in,
                              void* d_out, int out_size, void* d_ws, size_t ws_size,
                              hipStream_t stream) {
    const float* h   = (const float*)d_in[0];
    const float* raw = (const float*)d_in[1];
    float* out = (float*)d_out;
    int M = in_sizes[0];            // 4000
    int G = (M + TT - 1) / TT;      // 250 chunks

    char* ws = (char*)d_ws;
    size_t off = 0;
    auto take = [&](size_t bytes) { size_t cur = off; off = (off + bytes + 255) & ~(size_t)255; return cur; };
    float*        PrefT  = (float*)(ws + take((size_t)(NN + 1) * NN * 4));
    float*        RowTot = (float*)(ws + take((size_t)NN * 4));
    int*          steps  = (int*)(ws + take((size_t)(M + 1) * 4));
    unsigned int* UD     = (unsigned int*)(ws + take((size_t)G * NN * 4));

    k_pref<<<NN, 256, 0, stream>>>(raw, PrefT, RowTot);
    k_chunk<<<G, 256, 0, stream>>>(h, M, steps, UD);
    k_main<<<G, 256, 0, stream>>>(h, steps, UD, PrefT, RowTot, out, M);
}